// Round 9
// baseline (70.073 us; speedup 1.0000x reference)
//
#include <hip/hip_runtime.h>
#include <hip/hip_bf16.h>
#include <stdint.h>

typedef __attribute__((ext_vector_type(8))) short bf16x8;
typedef __attribute__((ext_vector_type(4))) float f32x4;

__device__ __forceinline__ short f2bf(float x) {
    __hip_bfloat16 h = __float2bfloat16(x);   // native cvt on gfx950 (RNE)
    return __builtin_bit_cast(short, h);
}

__device__ __forceinline__ bf16x8 pack8(f32x4 a, f32x4 b) {
    bf16x8 r;
    r[0] = f2bf(a[0]); r[1] = f2bf(a[1]); r[2] = f2bf(a[2]); r[3] = f2bf(a[3]);
    r[4] = f2bf(b[0]); r[5] = f2bf(b[1]); r[6] = f2bf(b[2]); r[7] = f2bf(b[3]);
    return r;
}

// ---------------------------------------------------------------------------
// Kernel C: repack Wq (1024x48 f32) into bf16 B-fragment layout.
// ---------------------------------------------------------------------------
__global__ __launch_bounds__(256) void prep_wfrag(const float* __restrict__ Wq,
                                                  short* __restrict__ wfrag) {
    int idx = blockIdx.x * 256 + threadIdx.x;   // 0..49151
    int j    = idx & 7;
    int lane = (idx >> 3) & 63;
    int grp  = idx >> 9;          // ks*3+nf
    int nf   = grp % 3;
    int ks   = grp / 3;
    int k = ks * 32 + ((lane >> 4) << 3) + j;
    int n = nf * 16 + (lane & 15);
    wfrag[idx] = f2bf(Wq[k * 48 + n]);
}

// ---------------------------------------------------------------------------
// Kernel A: qk = Q @ Wq + bq  (M=32768, N=48, K=1024), MFMA 16x16x32 bf16.
// Epilogue scatter-stores bf16 weights into A-frag-friendly layout:
//   wgtA[b][k][dg(128)][h(16)][8]  (dg = d>>3, j = d&7)
// ---------------------------------------------------------------------------
__global__ __launch_bounds__(256) void qk_gemm(const float* __restrict__ Q,
                                               const short* __restrict__ wfrag,
                                               const float* __restrict__ bq,
                                               short* __restrict__ wgtA) {
    const int l  = threadIdx.x & 63;
    const int w  = threadIdx.x >> 6;
    const int lr = l & 15;
    const int lk = l >> 4;
    const int row0 = blockIdx.x * 64 + w * 16;

    f32x4 acc[3];
    acc[0] = (f32x4){0.f, 0.f, 0.f, 0.f};
    acc[1] = acc[0];
    acc[2] = acc[0];

    const float* qbase = Q + (size_t)(row0 + lr) * 1024 + lk * 8;

    #pragma unroll 4
    for (int ks = 0; ks < 32; ++ks) {
        const float* p = qbase + ks * 32;
        f32x4 q0 = *(const f32x4*)p;
        f32x4 q1 = *(const f32x4*)(p + 4);
        bf16x8 a = pack8(q0, q1);
        const bf16x8* wp = (const bf16x8*)(wfrag + (size_t)ks * 1536 + l * 8);
        acc[0] = __builtin_amdgcn_mfma_f32_16x16x32_bf16(a, wp[0],   acc[0], 0, 0, 0);
        acc[1] = __builtin_amdgcn_mfma_f32_16x16x32_bf16(a, wp[64],  acc[1], 0, 0, 0);
        acc[2] = __builtin_amdgcn_mfma_f32_16x16x32_bf16(a, wp[128], acc[2], 0, 0, 0);
    }

    #pragma unroll
    for (int nf = 0; nf < 3; ++nf) {
        int n = nf * 16 + lr;
        float bias = bq[n];
        int t  = n / 3;
        int kk = n - t * 3;
        #pragma unroll
        for (int r = 0; r < 4; ++r) {
            int row = row0 + lk * 4 + r;
            int b   = row >> 10;
            int h   = (row >> 6) & 15;
            int sp  = row & 63;
            int dg  = sp * 2 + (t >> 3);
            int j   = t & 7;
            wgtA[(((size_t)(b * 3 + kk) * 128 + dg) << 7) + h * 8 + j] = f2bf(acc[nf][r] + bias);
        }
    }
}

// ---------------------------------------------------------------------------
// Kernel B v9 = v7 structure + depth-2 key prefetch.
//  - A-frag parity prefetch ONE STEP AHEAD (issued before next key LOADS ->
//    MFMA waitcnt never drains the key pipeline)   [v7, proven -30%]
//  - key register prefetch depth 2 (two parity sets, ~2 iters latency cover)
//  - XCD-aware block swizzle (wgt L2-resident)
//  - wave-private LDS dbuf, no barriers in loop
// Grid 1024 blocks (32 b x 32 st), 256 thr; wave = 16h x 16s, d-half.
// ---------------------------------------------------------------------------
__global__ __launch_bounds__(256, 3) void conv_mfma(const float* __restrict__ Key,
                                                    const short* __restrict__ wgtA,
                                                    float* __restrict__ out) {
    __shared__ short klds[4][2][18][64];   // 4 waves x dbuf x 18 rows x 128B
    __shared__ float red[2][16][17];
    const int blk = (blockIdx.x & 7) * 128 + (blockIdx.x >> 3);  // bijective XCD swizzle
    const int st  = blk & 31;
    const int b   = blk >> 5;
    const int tid = threadIdx.x;
    const int l   = tid & 63;
    const int w   = tid >> 6;
    const int lr  = l & 15;
    const int lk  = l >> 4;
    const int ss  = w & 1;
    const int dh  = w >> 1;
    const int sbase = (st << 5) + (ss << 4);

    const int row16 = l >> 2;
    const int cg    = l & 3;
    const int rowX  = 16 + (l >> 2);        // meaningful for l<8
    const int srowA = sbase - 1 + row16;
    const int srowX = sbase + 15 + (l >> 2);
    const bool okA  = (srowA >= 0);
    const bool okX  = (l < 8) && (srowX < 1024);

    const float* keyW = Key + ((size_t)b << 20) + (dh << 9);
    const f32x4* pA = (const f32x4*)(keyW + (size_t)(okA ? srowA : 0) * 1024 + cg * 16);
    const f32x4* pX = (const f32x4*)(keyW + (size_t)(okX ? srowX : 0) * 1024 + cg * 16);

    char* ldsW = (char*)&klds[w][0][0][0];  // 4608B per wave, 2304B per buf
    const int swzA = (row16 & 7) << 4;
    const int swzX = (rowX & 7) << 4;

    const f32x4 z4 = (f32x4){0.f, 0.f, 0.f, 0.f};
    f32x4 mA0[4], mX0[4], mA1[4], mX1[4];

    #define LOADS(ma, mx, t) do {                                      \
        const int o = (t) * 16;                                        \
        ma[0] = okA ? pA[o]     : z4;  ma[1] = okA ? pA[o + 1] : z4;   \
        ma[2] = okA ? pA[o + 2] : z4;  ma[3] = okA ? pA[o + 3] : z4;   \
        mx[0] = okX ? pX[o]     : z4;  mx[1] = okX ? pX[o + 1] : z4;   \
        mx[2] = okX ? pX[o + 2] : z4;  mx[3] = okX ? pX[o + 3] : z4;   \
    } while (0)

    #define WRITES(buf, ma, mx) do {                                          \
        char* bb = ldsW + (buf) * 2304;                                       \
        *(bf16x8*)(bb + row16 * 128 + (((cg << 5))      ^ swzA)) = pack8(ma[0], ma[1]); \
        *(bf16x8*)(bb + row16 * 128 + (((cg << 5) + 16) ^ swzA)) = pack8(ma[2], ma[3]); \
        if (l < 8) {                                                          \
            *(bf16x8*)(bb + rowX * 128 + (((cg << 5))      ^ swzX)) = pack8(mx[0], mx[1]); \
            *(bf16x8*)(bb + rowX * 128 + (((cg << 5) + 16) ^ swzX)) = pack8(mx[2], mx[3]); \
        }                                                                     \
    } while (0)

    const short* wgtW = wgtA + (((size_t)b * 384 + (dh << 6) + lk) << 7) + lr * 8;

    #define ALOAD(arr, tt) do {                                               \
        arr[0] = *(const bf16x8*)(wgtW +         (tt) * 1024);                \
        arr[1] = *(const bf16x8*)(wgtW +         (tt) * 1024 + 512);          \
        arr[2] = *(const bf16x8*)(wgtW + 16384 + (tt) * 1024);                \
        arr[3] = *(const bf16x8*)(wgtW + 16384 + (tt) * 1024 + 512);          \
        arr[4] = *(const bf16x8*)(wgtW + 32768 + (tt) * 1024);                \
        arr[5] = *(const bf16x8*)(wgtW + 32768 + (tt) * 1024 + 512);          \
    } while (0)

    f32x4 acc = z4;
    bf16x8 awA[6], awB[6];

    // prologue: stage t0; key-prefetch t1 (set0) and t2 (set1); A for t0
    LOADS(mA0, mX0, 0);
    WRITES(0, mA0, mX0);
    LOADS(mA0, mX0, 1);
    LOADS(mA1, mX1, 2);
    ALOAD(awA, 0);

    #pragma unroll
    for (int t = 0; t < 8; ++t) {
        const int buf = t & 1;
        // A-frags for NEXT step, issued before this step's MFMAs and before
        // the next key LOADS (keeps vmcnt waits from draining key pipeline)
        if (t < 7) {
            if (t & 1) ALOAD(awA, t + 1); else ALOAD(awB, t + 1);
        }
        #pragma unroll
        for (int k = 0; k < 3; ++k) {
            const int row = lr + k;
            const char* rb = ldsW + buf * 2304 + row * 128;
            const int sw = (row & 7) << 4;
            #pragma unroll
            for (int kk = 0; kk < 2; ++kk) {
                bf16x8 kv = *(const bf16x8*)(rb + (((kk << 6) + (lk << 4)) ^ sw));
                bf16x8 a  = (t & 1) ? awB[k * 2 + kk] : awA[k * 2 + kk];
                acc = __builtin_amdgcn_mfma_f32_16x16x32_bf16(a, kv, acc, 0, 0, 0);
            }
        }
        if (t < 7) {
            if (t & 1) {
                WRITES(buf ^ 1, mA1, mX1);           // keys t+1 (loaded 2 iters ago)
                if (t < 5) LOADS(mA1, mX1, t + 3);
            } else {
                WRITES(buf ^ 1, mA0, mX0);
                if (t < 5) LOADS(mA0, mX0, t + 3);
            }
        }
    }
    #undef LOADS
    #undef WRITES
    #undef ALOAD

    // combine d-halves (single barrier in whole kernel)
    if (dh == 1) {
        #pragma unroll
        for (int r4 = 0; r4 < 4; ++r4) red[ss][lk * 4 + r4][lr] = acc[r4];
    }
    __syncthreads();
    if (dh == 0) {
        const int s = sbase + lr;
        #pragma unroll
        for (int r4 = 0; r4 < 4; ++r4) {
            int h = lk * 4 + r4;
            out[(((b << 4) + h) << 10) + s] = acc[r4] + red[ss][h][lr];
        }
    }
}

extern "C" void kernel_launch(void* const* d_in, const int* in_sizes, int n_in,
                              void* d_out, int out_size, void* d_ws, size_t ws_size,
                              hipStream_t stream) {
    const float* Q  = (const float*)d_in[0];
    const float* K  = (const float*)d_in[1];
    const float* Wq = (const float*)d_in[4];
    const float* bq = (const float*)d_in[5];
    float* outp = (float*)d_out;

    short* wfrag = (short*)d_ws;                      // 98304 B
    short* wgtA  = (short*)((char*)d_ws + 98304);     // 3145728 B

    hipLaunchKernelGGL(prep_wfrag, dim3(192),  dim3(256), 0, stream, Wq, wfrag);
    hipLaunchKernelGGL(qk_gemm,    dim3(512),  dim3(256), 0, stream, Q, wfrag, bq, wgtA);
    hipLaunchKernelGGL(conv_mfma,  dim3(1024), dim3(256), 0, stream, K, wgtA, outp);
}

// Round 10
// 60.210 us; speedup vs baseline: 1.1638x; 1.1638x over previous
//
#include <hip/hip_runtime.h>
#include <hip/hip_bf16.h>
#include <stdint.h>

typedef __attribute__((ext_vector_type(8))) short bf16x8;
typedef __attribute__((ext_vector_type(4))) float f32x4;

__device__ __forceinline__ short f2bf(float x) {
    __hip_bfloat16 h = __float2bfloat16(x);   // native cvt on gfx950 (RNE)
    return __builtin_bit_cast(short, h);
}

__device__ __forceinline__ bf16x8 pack8(f32x4 a, f32x4 b) {
    bf16x8 r;
    r[0] = f2bf(a[0]); r[1] = f2bf(a[1]); r[2] = f2bf(a[2]); r[3] = f2bf(a[3]);
    r[4] = f2bf(b[0]); r[5] = f2bf(b[1]); r[6] = f2bf(b[2]); r[7] = f2bf(b[3]);
    return r;
}

// direct HBM->LDS DMA: 64 lanes x 16B, LDS dest = uniform base + lane*16
#define GLDS(gp, lp) __builtin_amdgcn_global_load_lds( \
    (const __attribute__((address_space(1))) void*)(gp), \
    (__attribute__((address_space(3))) void*)(lp), 16, 0, 0)

// ---------------------------------------------------------------------------
// Kernel C: repack Wq (1024x48 f32) into bf16 B-fragment layout.
// ---------------------------------------------------------------------------
__global__ __launch_bounds__(256) void prep_wfrag(const float* __restrict__ Wq,
                                                  short* __restrict__ wfrag) {
    int idx = blockIdx.x * 256 + threadIdx.x;   // 0..49151
    int j    = idx & 7;
    int lane = (idx >> 3) & 63;
    int grp  = idx >> 9;          // ks*3+nf
    int nf   = grp % 3;
    int ks   = grp / 3;
    int k = ks * 32 + ((lane >> 4) << 3) + j;
    int n = nf * 16 + (lane & 15);
    wfrag[idx] = f2bf(Wq[k * 48 + n]);
}

// ---------------------------------------------------------------------------
// Kernel A: qk = Q @ Wq + bq  (M=32768, N=48, K=1024), MFMA 16x16x32 bf16.
// Epilogue scatter-stores bf16 weights into A-frag layout:
//   wgtA[b][k][dg(128)][h(16)][8]
// ---------------------------------------------------------------------------
__global__ __launch_bounds__(256) void qk_gemm(const float* __restrict__ Q,
                                               const short* __restrict__ wfrag,
                                               const float* __restrict__ bq,
                                               short* __restrict__ wgtA) {
    const int l  = threadIdx.x & 63;
    const int w  = threadIdx.x >> 6;
    const int lr = l & 15;
    const int lk = l >> 4;
    const int row0 = blockIdx.x * 64 + w * 16;

    f32x4 acc[3];
    acc[0] = (f32x4){0.f, 0.f, 0.f, 0.f};
    acc[1] = acc[0];
    acc[2] = acc[0];

    const float* qbase = Q + (size_t)(row0 + lr) * 1024 + lk * 8;

    #pragma unroll 4
    for (int ks = 0; ks < 32; ++ks) {
        const float* p = qbase + ks * 32;
        f32x4 q0 = *(const f32x4*)p;
        f32x4 q1 = *(const f32x4*)(p + 4);
        bf16x8 a = pack8(q0, q1);
        const bf16x8* wp = (const bf16x8*)(wfrag + (size_t)ks * 1536 + l * 8);
        acc[0] = __builtin_amdgcn_mfma_f32_16x16x32_bf16(a, wp[0],   acc[0], 0, 0, 0);
        acc[1] = __builtin_amdgcn_mfma_f32_16x16x32_bf16(a, wp[64],  acc[1], 0, 0, 0);
        acc[2] = __builtin_amdgcn_mfma_f32_16x16x32_bf16(a, wp[128], acc[2], 0, 0, 0);
    }

    #pragma unroll
    for (int nf = 0; nf < 3; ++nf) {
        int n = nf * 16 + lr;
        float bias = bq[n];
        int t  = n / 3;
        int kk = n - t * 3;
        #pragma unroll
        for (int r = 0; r < 4; ++r) {
            int row = row0 + lk * 4 + r;
            int b   = row >> 10;
            int h   = (row >> 6) & 15;
            int sp  = row & 63;
            int dg  = sp * 2 + (t >> 3);
            int j   = t & 7;
            wgtA[(((size_t)(b * 3 + kk) * 128 + dg) << 7) + h * 8 + j] = f2bf(acc[nf][r] + bias);
        }
    }
}

// ---------------------------------------------------------------------------
// Kernel B v10: global_load_lds staging + counted inline vmcnt (T3/T4).
// Grid 1024 (32 b x 32 st), 256 thr, 4 waves: ss=w&1 (s-sub 16), dh=w>>1
// (d-half 512). 16 steps x 32 d per half. Keys staged as f32, QUAD-buffered
// (4 x 36 rows x 256B = 36.9 KB): 3 stage batches in flight, issued BEFORE
// the wait. Wave 0 stages (9 global_load_lds dwordx4 / step). LDS swizzle
// via inverse-XOR'd global source + XOR'd read (rule 21). f32->bf16 at
// frag-build. Raw s_barrier (no vmcnt-draining __syncthreads) in loop.
// ---------------------------------------------------------------------------
__global__ __launch_bounds__(256, 4) void conv_mfma(const float* __restrict__ Key,
                                                    const short* __restrict__ wgtA,
                                                    float* __restrict__ out) {
    __shared__ char stage[4 * 9216];      // 36864 B
    __shared__ float red[2][16][17];      //  2176 B
    const int blk = (blockIdx.x & 7) * 128 + (blockIdx.x >> 3);  // XCD swizzle
    const int st  = blk & 31;
    const int b   = blk >> 5;
    const int tid = threadIdx.x;
    const int l   = tid & 63;
    const int w   = tid >> 6;
    const int lr  = l & 15;
    const int lk  = l >> 4;
    const int ss  = w & 1;
    const int dh  = w >> 1;
    const int s0  = st << 5;

    // per-lane staging sources (used by wave 0): instruction i covers rows
    // 4i..4i+3; lane l -> row 4i+(l>>4), LDS slot byte (l&15)*16 within the
    // 256B row. Source byte = slot ^ ((row&7)<<4)  [inverse swizzle], then
    // mapped: byte<128 -> d-half 0 (d=t*32+..), >=128 -> half 1 (d=512+t*32+..)
    const char* gaddr[9];
    {
        const char* keyB = (const char*)(Key + ((size_t)b << 20));
        int cb = (l & 15) << 4;
        #pragma unroll
        for (int i = 0; i < 9; ++i) {
            int grow = i * 4 + (l >> 4);           // 0..35
            int srow = s0 - 1 + grow;
            srow = srow < 0 ? 0 : (srow > 1023 ? 1023 : srow);
            int gb   = cb ^ ((grow & 7) << 4);
            int colb = gb + ((gb >> 7) * 1920);    // gb>=128: 2048+(gb-128)
            gaddr[i] = keyB + (size_t)srow * 4096 + colb;
        }
    }

    const short* wgtW = wgtA + (((size_t)b * 384 + (dh << 6) + lk) << 7) + lr * 8;
    bf16x8 aw0[3], aw1[3];
    f32x4 acc = (f32x4){0.f, 0.f, 0.f, 0.f};

    #define ALOADV(arr, tt) do{ _Pragma("unroll") \
        for (int k3 = 0; k3 < 3; ++k3) \
            arr[k3] = *(const bf16x8*)(wgtW + k3 * 16384 + (tt) * 512); }while(0)

    #define STAGEV(tt) do{ char* bb_ = stage + ((tt) & 3) * 9216; _Pragma("unroll") \
        for (int i9 = 0; i9 < 9; ++i9) GLDS(gaddr[i9] + (tt) * 128, bb_ + i9 * 1024); }while(0)

    #define ZFIX(tt) do{ \
        if (st == 0  && l < 16) *(f32x4*)(stage + ((tt)&3)*9216 + (l<<4)) = (f32x4){0.f,0.f,0.f,0.f}; \
        if (st == 31 && l < 16) *(f32x4*)(stage + ((tt)&3)*9216 + 33*256 + (l<<4)) = (f32x4){0.f,0.f,0.f,0.f}; \
        if (st == 0 || st == 31) asm volatile("s_waitcnt lgkmcnt(0)" ::: "memory"); }while(0)

    #define COMP(tt) do{ \
        const char* bb_ = stage + ((tt) & 3) * 9216; \
        _Pragma("unroll") for (int k3 = 0; k3 < 3; ++k3) { \
            int row_ = ss * 16 + lr + k3; \
            const char* rb_ = bb_ + row_ * 256; \
            int sw_ = (row_ & 7) << 4; \
            int x_  = (dh << 7) + (lk << 5); \
            f32x4 v0_ = *(const f32x4*)(rb_ + ((x_) ^ sw_)); \
            f32x4 v1_ = *(const f32x4*)(rb_ + ((x_ + 16) ^ sw_)); \
            bf16x8 a_ = ((tt) & 1) ? aw1[k3] : aw0[k3]; \
            acc = __builtin_amdgcn_mfma_f32_16x16x32_bf16(a_, pack8(v0_, v1_), acc, 0, 0, 0); \
        } }while(0)

    // step: [A(t+1)] [S(t+3)] [counted vmcnt] [barrier] [compute] [barrier]
    // wave0 vmcnt: newer-than-A(t) = S(t+2)+A(t+1)+S(t+3) = 21 steady;
    // tails 12/3/0. other waves: only A-loads in queue -> 3 / 0.
    #define STEP(tt, NW0, NWX) do{ \
        if ((tt) < 15) { if ((tt) & 1) ALOADV(aw0, (tt)+1); else ALOADV(aw1, (tt)+1); } \
        if (w == 0) { \
            if ((tt) < 13) STAGEV((tt) + 3); \
            asm volatile("s_waitcnt vmcnt(" NW0 ")" ::: "memory"); \
            ZFIX(tt); \
        } else { \
            asm volatile("s_waitcnt vmcnt(" NWX ")" ::: "memory"); \
        } \
        __builtin_amdgcn_s_barrier(); \
        asm volatile("" ::: "memory"); \
        COMP(tt); \
        asm volatile("" ::: "memory"); \
        __builtin_amdgcn_s_barrier(); }while(0)

    // prologue: 3 stage batches in flight + A(0)
    if (w == 0) { STAGEV(0); STAGEV(1); STAGEV(2); }
    ALOADV(aw0, 0);

    STEP(0,  "21", "3");  STEP(1,  "21", "3");  STEP(2,  "21", "3");
    STEP(3,  "21", "3");  STEP(4,  "21", "3");  STEP(5,  "21", "3");
    STEP(6,  "21", "3");  STEP(7,  "21", "3");  STEP(8,  "21", "3");
    STEP(9,  "21", "3");  STEP(10, "21", "3");  STEP(11, "21", "3");
    STEP(12, "21", "3");  STEP(13, "12", "3");  STEP(14, "3",  "3");
    STEP(15, "0",  "0");

    #undef ALOADV
    #undef STAGEV
    #undef ZFIX
    #undef COMP
    #undef STEP

    // combine d-halves
    if (dh == 1) {
        #pragma unroll
        for (int r4 = 0; r4 < 4; ++r4) red[ss][lk * 4 + r4][lr] = acc[r4];
    }
    __syncthreads();
    if (dh == 0) {
        const int s = s0 + ss * 16 + lr;
        #pragma unroll
        for (int r4 = 0; r4 < 4; ++r4) {
            int h = lk * 4 + r4;
            out[(((b << 4) + h) << 10) + s] = acc[r4] + red[ss][h][lr];
        }
    }
}

extern "C" void kernel_launch(void* const* d_in, const int* in_sizes, int n_in,
                              void* d_out, int out_size, void* d_ws, size_t ws_size,
                              hipStream_t stream) {
    const float* Q  = (const float*)d_in[0];
    const float* K  = (const float*)d_in[1];
    const float* Wq = (const float*)d_in[4];
    const float* bq = (const float*)d_in[5];
    float* outp = (float*)d_out;

    short* wfrag = (short*)d_ws;                      // 98304 B
    short* wgtA  = (short*)((char*)d_ws + 98304);     // 3145728 B

    hipLaunchKernelGGL(prep_wfrag, dim3(192),  dim3(256), 0, stream, Wq, wfrag);
    hipLaunchKernelGGL(qk_gemm,    dim3(512),  dim3(256), 0, stream, Q, wfrag, bq, wgtA);
    hipLaunchKernelGGL(conv_mfma,  dim3(1024), dim3(256), 0, stream, K, wgtA, outp);
}